// Round 2
// baseline (9753.780 us; speedup 1.0000x reference)
//
#include <hip/hip_runtime.h>
#include <hip/hip_bf16.h>

// Problem constants (GPT forward):
#define VV     50257
#define DMODEL 384
#define NH     6
#define HSZ    64
#define NL     6
#define TSEQ   256
#define BBAT   8
#define MROWS  (BBAT*TSEQ)   // 2048
#define LNEPS  1e-5f

// emb[t,j] from _rope_sincos: j even -> sin(t*div[j/2]); j odd -> cos(t*div[(j-1)/2])
// div[m] = exp(2m * (-ln(10000)/64))
__device__ __forceinline__ float rope_emb(int t, int j) {
    int m = j >> 1;
    float div = expf((2.0f * (float)m) * (-logf(10000.0f) / 64.0f));
    float ang = (float)t * div;
    return (j & 1) ? cosf(ang) : sinf(ang);
}

// ---------------- embedding gather ----------------
__global__ void embed_kernel(const int* __restrict__ idx, const float* __restrict__ tok,
                             float* __restrict__ x) {
    int i = blockIdx.x * blockDim.x + threadIdx.x;
    if (i < MROWS * DMODEL) {
        int row = i / DMODEL, col = i % DMODEL;
        x[i] = tok[(size_t)idx[row] * DMODEL + col];
    }
}

// ---------------- layernorm (one block per row, 384 threads) ----------------
__global__ void ln_kernel(const float* __restrict__ x, const float* __restrict__ g,
                          const float* __restrict__ b, float* __restrict__ out) {
    int row = blockIdx.x;
    int j = threadIdx.x;               // 0..383
    float v = x[row * DMODEL + j];
    float sum = v, sq = v * v;
    __shared__ float s_sum[6], s_sq[6];
    int wave = j >> 6, lane = j & 63;
    #pragma unroll
    for (int off = 32; off; off >>= 1) {
        sum += __shfl_down(sum, off);
        sq  += __shfl_down(sq, off);
    }
    if (lane == 0) { s_sum[wave] = sum; s_sq[wave] = sq; }
    __syncthreads();
    if (j == 0) {
        float ts = 0.f, tq = 0.f;
        #pragma unroll
        for (int w = 0; w < 6; w++) { ts += s_sum[w]; tq += s_sq[w]; }
        float mu = ts / (float)DMODEL;
        float var = tq / (float)DMODEL - mu * mu;
        s_sum[0] = mu;
        s_sq[0] = rsqrtf(var + LNEPS);
    }
    __syncthreads();
    float mu = s_sum[0], r = s_sq[0];
    out[row * DMODEL + j] = (v - mu) * r * g[j] + b[j];
}

// ---------------- QKV projection + RoPE (block: 64 threads = one (bt,h) row) ----------------
__global__ void qkv_kernel(const float* __restrict__ xn,
                           const float* __restrict__ Wq, const float* __restrict__ Wk,
                           const float* __restrict__ Wv,
                           float* __restrict__ q, float* __restrict__ k, float* __restrict__ v) {
    int bt = blockIdx.x;           // 0..2047
    int h  = blockIdx.y;           // 0..5
    int j  = threadIdx.x;          // 0..63
    int t  = bt % TSEQ;

    __shared__ float sx[DMODEL];
    const float* xr = xn + bt * DMODEL;
    for (int i = j; i < DMODEL; i += 64) sx[i] = xr[i];
    __syncthreads();

    const float* wq = Wq + (size_t)(h * DMODEL) * HSZ + j;
    const float* wk = Wk + (size_t)(h * DMODEL) * HSZ + j;
    const float* wv = Wv + (size_t)(h * DMODEL) * HSZ + j;
    float aq = 0.f, ak = 0.f, av = 0.f;
    for (int d = 0; d < DMODEL; d++) {
        float xv = sx[d];
        aq += xv * wq[d * HSZ];
        ak += xv * wk[d * HSZ];
        av += xv * wv[d * HSZ];
    }
    // RoPE pair mix: out[2i] = -raw[2i+1]*emb(t,32+i); out[2i+1] = raw[2i]*emb(t,i)
    float pq = __shfl_xor(aq, 1);
    float pk = __shfl_xor(ak, 1);
    int i2 = j >> 1;
    float e = (j & 1) ? rope_emb(t, i2) : rope_emb(t, 32 + i2);
    float rq = (j & 1) ? (pq * e) : (-pq * e);
    float rk = (j & 1) ? (pk * e) : (-pk * e);

    int bh = (bt / TSEQ) * NH + h;
    int o = (bh * TSEQ + t) * HSZ + j;
    q[o] = rq;
    k[o] = rk;
    v[o] = av;
}

// ---------------- causal attention, online softmax (block = one (b,h); thread = query row) ----
__global__ void attn_kernel(const float* __restrict__ q, const float* __restrict__ k,
                            const float* __restrict__ v, float* __restrict__ att) {
    int bh = blockIdx.x;           // 0..47
    int t  = threadIdx.x;          // 0..255
    int b = bh / NH, h = bh % NH;

    const float* qr = q + (bh * TSEQ + t) * HSZ;
    float qreg[HSZ];
    #pragma unroll
    for (int i = 0; i < HSZ; i++) qreg[i] = qr[i];

    float m = -1e30f, l = 0.f;
    float acc[HSZ];
    #pragma unroll
    for (int i = 0; i < HSZ; i++) acc[i] = 0.f;
    const float scale = 0.125f;    // 64^-0.5

    for (int s = 0; s <= t; s++) {
        const float* kr = k + (bh * TSEQ + s) * HSZ;
        float w = 0.f;
        #pragma unroll
        for (int i = 0; i < HSZ; i++) w += qreg[i] * kr[i];
        w *= scale;
        float mn = fmaxf(m, w);
        float corr = expf(m - mn);
        float p = expf(w - mn);
        l = l * corr + p;
        const float* vr = v + (bh * TSEQ + s) * HSZ;
        #pragma unroll
        for (int i = 0; i < HSZ; i++) acc[i] = acc[i] * corr + p * vr[i];
        m = mn;
    }
    float inv = 1.f / l;
    // write in (B, T, H*HS) layout for the projection GEMM
    float* ar = att + ((b * TSEQ + t) * NH + h) * HSZ;
    #pragma unroll
    for (int i = 0; i < HSZ; i++) ar[i] = acc[i] * inv;
}

// ---------------- generic tiled GEMM: C = A(MxK) @ W(KxN) + bias [+res] [ReLU] ----
// 256 threads, 64x64 tile, BK=16, 4x4 micro-tile per thread. All fp32.
template<bool RELU, bool RES>
__global__ void gemm_kernel(const float* __restrict__ A, const float* __restrict__ W,
                            const float* __restrict__ bias, const float* res,
                            float* __restrict__ outp,
                            int Mdim, int Ndim, int Kdim) {
    __shared__ float As[16][64 + 1];
    __shared__ float Bs[16][64 + 1];
    int tid = threadIdx.x;
    int tx = tid & 15, ty = tid >> 4;
    int row0 = blockIdx.y * 64;
    int col0 = blockIdx.x * 64;

    float acc[4][4];
    #pragma unroll
    for (int i = 0; i < 4; i++)
        #pragma unroll
        for (int j = 0; j < 4; j++) acc[i][j] = 0.f;

    for (int k0 = 0; k0 < Kdim; k0 += 16) {
        // A tile: 64 rows x 16 cols (M divisible by 64, K divisible by 16)
        for (int i = tid; i < 64 * 16; i += 256) {
            int r = i >> 4, c = i & 15;
            As[c][r] = A[(size_t)(row0 + r) * Kdim + (k0 + c)];
        }
        // B tile: 16 rows x 64 cols
        for (int i = tid; i < 16 * 64; i += 256) {
            int r = i >> 6, c = i & 63;
            int gc = col0 + c;
            Bs[r][c] = (gc < Ndim) ? W[(size_t)(k0 + r) * Ndim + gc] : 0.f;
        }
        __syncthreads();
        #pragma unroll
        for (int kk = 0; kk < 16; kk++) {
            float a[4], bb[4];
            #pragma unroll
            for (int i = 0; i < 4; i++) a[i] = As[kk][ty * 4 + i];
            #pragma unroll
            for (int j = 0; j < 4; j++) bb[j] = Bs[kk][tx * 4 + j];
            #pragma unroll
            for (int i = 0; i < 4; i++)
                #pragma unroll
                for (int j = 0; j < 4; j++) acc[i][j] += a[i] * bb[j];
        }
        __syncthreads();
    }

    #pragma unroll
    for (int i = 0; i < 4; i++) {
        int gr = row0 + ty * 4 + i;
        #pragma unroll
        for (int j = 0; j < 4; j++) {
            int gc = col0 + tx * 4 + j;
            if (gc >= Ndim) continue;
            float vout = acc[i][j] + bias[gc];
            if (RELU) vout = fmaxf(vout, 0.f);
            if (RES)  vout += res[(size_t)gr * Ndim + gc];
            outp[(size_t)gr * Ndim + gc] = vout;
        }
    }
}

extern "C" void kernel_launch(void* const* d_in, const int* in_sizes, int n_in,
                              void* d_out, int out_size, void* d_ws, size_t ws_size,
                              hipStream_t stream) {
    const int*   idx  = (const int*)d_in[0];
    const float* tok  = (const float*)d_in[1];
    const float* Wq   = (const float*)d_in[2];
    const float* Wk   = (const float*)d_in[3];
    const float* Wv   = (const float*)d_in[4];
    const float* Wp   = (const float*)d_in[5];
    const float* bp   = (const float*)d_in[6];
    const float* W1   = (const float*)d_in[7];
    const float* b1   = (const float*)d_in[8];
    const float* W2   = (const float*)d_in[9];
    const float* b2   = (const float*)d_in[10];
    const float* ln1g = (const float*)d_in[11];
    const float* ln1b = (const float*)d_in[12];
    const float* ln2g = (const float*)d_in[13];
    const float* ln2b = (const float*)d_in[14];
    const float* lnfg = (const float*)d_in[15];
    const float* lnfb = (const float*)d_in[16];
    const float* lmW  = (const float*)d_in[17];
    const float* lmb  = (const float*)d_in[18];
    float* out = (float*)d_out;

    const int ND = MROWS * DMODEL;       // 786432
    float* x   = (float*)d_ws;
    float* xn  = x   + ND;
    float* q   = xn  + ND;
    float* kbuf= q   + ND;
    float* vbuf= kbuf+ ND;
    float* att = vbuf+ ND;
    float* h1  = att + ND;               // 2048*1536

    embed_kernel<<<(ND + 255) / 256, 256, 0, stream>>>(idx, tok, x);

    for (int l = 0; l < NL; l++) {
        ln_kernel<<<MROWS, DMODEL, 0, stream>>>(x, ln1g + l * DMODEL, ln1b + l * DMODEL, xn);
        qkv_kernel<<<dim3(MROWS, NH), 64, 0, stream>>>(
            xn, Wq + (size_t)l * NH * DMODEL * HSZ, Wk + (size_t)l * NH * DMODEL * HSZ,
            Wv + (size_t)l * NH * DMODEL * HSZ, q, kbuf, vbuf);
        attn_kernel<<<BBAT * NH, TSEQ, 0, stream>>>(q, kbuf, vbuf, att);
        gemm_kernel<false, true><<<dim3(DMODEL / 64, MROWS / 64), 256, 0, stream>>>(
            att, Wp + (size_t)l * DMODEL * DMODEL, bp + l * DMODEL, x, x,
            MROWS, DMODEL, DMODEL);
        ln_kernel<<<MROWS, DMODEL, 0, stream>>>(x, ln2g + l * DMODEL, ln2b + l * DMODEL, xn);
        gemm_kernel<true, false><<<dim3(4 * DMODEL / 64, MROWS / 64), 256, 0, stream>>>(
            xn, W1 + (size_t)l * DMODEL * 4 * DMODEL, b1 + l * 4 * DMODEL, nullptr, h1,
            MROWS, 4 * DMODEL, DMODEL);
        gemm_kernel<false, true><<<dim3(DMODEL / 64, MROWS / 64), 256, 0, stream>>>(
            h1, W2 + (size_t)l * 4 * DMODEL * DMODEL, b2 + l * DMODEL, x, x,
            MROWS, DMODEL, 4 * DMODEL);
    }

    ln_kernel<<<MROWS, DMODEL, 0, stream>>>(x, lnfg, lnfb, xn);
    gemm_kernel<false, false><<<dim3((VV + 63) / 64, MROWS / 64), 256, 0, stream>>>(
        xn, lmW, lmb, nullptr, out, MROWS, VV, DMODEL);
}